// Round 7
// baseline (1494.441 us; speedup 1.0000x reference)
//
#include <hip/hip_runtime.h>
#include <stdint.h>
#include <math.h>

// RWKV-6 TimeMix forward, MI355X gfx950.
// B=4 T=2048 C=2048 H=32 K=64, chunk len 32, N=64 chunks, M=B*T=8192.
// Workspace footprint: 208 MiB (phase-disjoint aliasing; see layout below).
// d_out region doubles as scratch for xbf/dxbf until k_chunk rewrites it.

typedef __attribute__((ext_vector_type(8))) short bf16x8;
typedef __attribute__((ext_vector_type(4))) float f32x4;

#define AS1(p) ((const __attribute__((address_space(1))) void*)(p))
#define AS3(p) ((__attribute__((address_space(3))) void*)(p))

__device__ __forceinline__ unsigned short f2bf(float f) {
  unsigned int u = __builtin_bit_cast(unsigned int, f);
  u += 0x7fffu + ((u >> 16) & 1u);
  return (unsigned short)(u >> 16);
}
__device__ __forceinline__ float bf2f(unsigned short s) {
  unsigned int u = ((unsigned int)s) << 16;
  return __builtin_bit_cast(float, u);
}
__device__ __forceinline__ unsigned int packbf(float lo, float hi) {
  return (unsigned int)f2bf(lo) | ((unsigned int)f2bf(hi) << 16);
}

// ---------------- generic NT GEMM: C[m,n] = sum_k A[m,k]*B[n,k], bf16 in ----
// EPI: 0 f32 std, 2 tanh->bf16 std, 3 silu->bf16 std, 4 wlog->f16 std,
//      5 bf16 chunk-record (slot = 0 r, 2048 k, 4096 v)
// (kept for the small/bounded shapes: xxx, t1, wlog)
template <int EPI, bool BOUNDS>
__global__ __launch_bounds__(256) void gemm_nt(
    const unsigned short* __restrict__ A, const unsigned short* __restrict__ B,
    void* __restrict__ Cp, int M, int N, int K, const float* __restrict__ evec,
    int slot)
{
  __shared__ __align__(16) unsigned short As[128 * 32];
  __shared__ __align__(16) unsigned short Bs[128 * 32];
  const int tid = threadIdx.x;
  const int l = tid & 63, w = tid >> 6;
  const int wm = w & 1, wn = w >> 1;
  const int lm = l & 15, quad = l >> 4;
  const long mBase = (long)blockIdx.y * 128;
  const long nBase = (long)blockIdx.x * 128;

  f32x4 acc[4][4];
  f32x4 zero = {0.f, 0.f, 0.f, 0.f};
#pragma unroll
  for (int i = 0; i < 4; i++)
#pragma unroll
    for (int j = 0; j < 4; j++) acc[i][j] = zero;

  for (int k0 = 0; k0 < K; k0 += 32) {
    if (!BOUNDS) {
      const int r0 = w * 32;
      const int lr = l >> 2, lc = l & 3;
      const unsigned short* gA = A + (mBase + r0 + lr) * (long)K + k0 + lc * 8;
      __builtin_amdgcn_global_load_lds(AS1(gA), AS3(&As[r0 * 32]), 16, 0, 0);
      const unsigned short* gA2 = gA + 16 * (long)K;
      __builtin_amdgcn_global_load_lds(AS1(gA2), AS3(&As[(r0 + 16) * 32]), 16, 0, 0);
      const unsigned short* gB = B + (nBase + r0 + lr) * (long)K + k0 + lc * 8;
      __builtin_amdgcn_global_load_lds(AS1(gB), AS3(&Bs[r0 * 32]), 16, 0, 0);
      const unsigned short* gB2 = gB + 16 * (long)K;
      __builtin_amdgcn_global_load_lds(AS1(gB2), AS3(&Bs[(r0 + 16) * 32]), 16, 0, 0);
    } else {
      const int row = tid >> 2, ch = tid & 3;
#pragma unroll
      for (int rr = 0; rr < 128; rr += 64) {
        int r = rr + row;
        *(int4*)&As[r * 32 + ch * 8] =
            *(const int4*)&A[(mBase + r) * (long)K + k0 + ch * 8];
        int4 bv = make_int4(0, 0, 0, 0);
        long nG = nBase + r;
        if (nG < N) bv = *(const int4*)&B[nG * (long)K + k0 + ch * 8];
        *(int4*)&Bs[r * 32 + ch * 8] = bv;
      }
    }
    __syncthreads();
    bf16x8 af[4], bq[4];
#pragma unroll
    for (int i = 0; i < 4; i++)
      af[i] = *(const bf16x8*)&As[(wm * 64 + i * 16 + lm) * 32 + quad * 8];
#pragma unroll
    for (int i = 0; i < 4; i++)
      bq[i] = *(const bf16x8*)&Bs[(wn * 64 + i * 16 + lm) * 32 + quad * 8];
#pragma unroll
    for (int mi = 0; mi < 4; mi++)
#pragma unroll
      for (int ni = 0; ni < 4; ni++)
        acc[mi][ni] = __builtin_amdgcn_mfma_f32_16x16x32_bf16(af[mi], bq[ni], acc[mi][ni], 0, 0, 0);
    __syncthreads();
  }

#pragma unroll
  for (int mi = 0; mi < 4; mi++) {
#pragma unroll
    for (int ni = 0; ni < 4; ni++) {
      long col = nBase + wn * 64 + ni * 16 + lm;
      if (BOUNDS && col >= N) continue;
      long rw0 = mBase + wm * 64 + mi * 16 + quad * 4;
#pragma unroll
      for (int r = 0; r < 4; r++) {
        float y = acc[mi][ni][r];
        long row = rw0 + r;
        long off = row * (long)N + col;
        if constexpr (EPI == 0) {
          ((float*)Cp)[off] = y;
        } else if constexpr (EPI == 2) {
          ((unsigned short*)Cp)[off] = f2bf(tanhf(y));
        } else if constexpr (EPI == 3) {
          ((unsigned short*)Cp)[off] = f2bf(y / (1.f + __expf(-y)));
        } else if constexpr (EPI == 4) {
          float wv = evec[col] + y;
          ((_Float16*)Cp)[off] = (_Float16)fmaxf(-__expf(wv), -5.2983174f);
        } else if constexpr (EPI == 5) {
          int b = (int)(row >> 11), t = (int)(row & 2047);
          int n = t >> 5, tt = t & 31;
          int h = (int)(col >> 6), kk = (int)(col & 63);
          long c = ((long)(b * 32 + h)) * 64 + n;
          ((unsigned short*)Cp)[c * 6144 + slot + tt * 64 + kk] = f2bf(y);
        }
      }
    }
  }
}

// ---------------- 256x256 deep-pipelined NT GEMM (big shapes only) ----------
// Requirements: M%256==0, N%256==0, K%64==0, K>=128.
template <int EPI>
__global__ __launch_bounds__(512, 1) void gemm256_nt(
    const unsigned short* __restrict__ A, const unsigned short* __restrict__ B,
    void* __restrict__ Cp, int M, int N, int K, int slot)
{
  __shared__ __align__(16) unsigned short As2[2][16384];
  __shared__ __align__(16) unsigned short Bs2[2][16384];
  const int tid = threadIdx.x;
  const int l = tid & 63;
  const int w = tid >> 6;
  const int wm = w >> 2, wn = w & 3;
  const int lm = l & 15, quad = l >> 4;
  const long mBase = (long)blockIdx.y * 256;
  const long nBase = (long)blockIdx.x * 256;
  const int NT = K >> 6;

  const int r0 = tid >> 3;
  const int csw = (tid & 7) ^ (r0 & 7);
  const int ldsOff = (tid & ~63) * 8;
  const unsigned short* ga0 = A + (mBase + r0) * (long)K + csw * 8;
  const unsigned short* gb0 = B + (nBase + r0) * (long)K + csw * 8;

  f32x4 acc[8][4];
  f32x4 zero = {0.f, 0.f, 0.f, 0.f};
#pragma unroll
  for (int i = 0; i < 8; i++)
#pragma unroll
    for (int j = 0; j < 4; j++) acc[i][j] = zero;

#define STAGE256(kt_)                                                          \
  {                                                                            \
    const int _b = (kt_) & 1;                                                  \
    const unsigned short* _ga = ga0 + (long)(kt_) * 64;                        \
    const unsigned short* _gb = gb0 + (long)(kt_) * 64;                        \
    __builtin_amdgcn_global_load_lds(AS1(_ga), AS3(&As2[_b][ldsOff]), 16, 0, 0);              \
    __builtin_amdgcn_global_load_lds(AS1(_gb), AS3(&Bs2[_b][ldsOff]), 16, 0, 0);              \
    __builtin_amdgcn_global_load_lds(AS1(_ga + (long)64 * K), AS3(&As2[_b][4096 + ldsOff]), 16, 0, 0);  \
    __builtin_amdgcn_global_load_lds(AS1(_gb + (long)64 * K), AS3(&Bs2[_b][4096 + ldsOff]), 16, 0, 0);  \
    __builtin_amdgcn_global_load_lds(AS1(_ga + (long)128 * K), AS3(&As2[_b][8192 + ldsOff]), 16, 0, 0); \
    __builtin_amdgcn_global_load_lds(AS1(_gb + (long)128 * K), AS3(&Bs2[_b][8192 + ldsOff]), 16, 0, 0); \
    __builtin_amdgcn_global_load_lds(AS1(_ga + (long)192 * K), AS3(&As2[_b][12288 + ldsOff]), 16, 0, 0);\
    __builtin_amdgcn_global_load_lds(AS1(_gb + (long)192 * K), AS3(&Bs2[_b][12288 + ldsOff]), 16, 0, 0);\
  }

  STAGE256(0);
  STAGE256(1);
  asm volatile("s_waitcnt vmcnt(8)" ::: "memory");
  __builtin_amdgcn_s_barrier();

  const int q0 = (quad ^ (lm & 7)) * 8;
  const int rA = (wm * 128 + lm) * 64;
  const int rB = (wn * 64 + lm) * 64;

  for (int kt = 0; kt < NT; ++kt) {
    const int b = kt & 1;
    bf16x8 af[8][2], bq[4][2];
#pragma unroll
    for (int fm = 0; fm < 8; fm++)
      af[fm][0] = *(const bf16x8*)&As2[b][rA + fm * 1024 + q0];
#pragma unroll
    for (int fn = 0; fn < 4; fn++)
      bq[fn][0] = *(const bf16x8*)&Bs2[b][rB + fn * 1024 + q0];
#pragma unroll
    for (int fm = 0; fm < 8; fm++)
      af[fm][1] = *(const bf16x8*)&As2[b][rA + fm * 1024 + (q0 ^ 32)];
#pragma unroll
    for (int fn = 0; fn < 4; fn++)
      bq[fn][1] = *(const bf16x8*)&Bs2[b][rB + fn * 1024 + (q0 ^ 32)];

    __builtin_amdgcn_s_setprio(1);
#pragma unroll
    for (int fm = 0; fm < 8; fm++)
#pragma unroll
      for (int fn = 0; fn < 4; fn++)
        acc[fm][fn] = __builtin_amdgcn_mfma_f32_16x16x32_bf16(af[fm][0], bq[fn][0], acc[fm][fn], 0, 0, 0);
    __builtin_amdgcn_s_setprio(0);

    asm volatile("s_waitcnt lgkmcnt(0)" ::: "memory");
    __builtin_amdgcn_s_barrier();  // (A)
    if (kt + 2 < NT) STAGE256(kt + 2);

    __builtin_amdgcn_s_setprio(1);
#pragma unroll
    for (int fm = 0; fm < 8; fm++)
#pragma unroll
      for (int fn = 0; fn < 4; fn++)
        acc[fm][fn] = __builtin_amdgcn_mfma_f32_16x16x32_bf16(af[fm][1], bq[fn][1], acc[fm][fn], 0, 0, 0);
    __builtin_amdgcn_s_setprio(0);

    if (kt + 2 < NT) {
      asm volatile("s_waitcnt vmcnt(8)" ::: "memory");
    } else {
      asm volatile("s_waitcnt vmcnt(0)" ::: "memory");
    }
    __builtin_amdgcn_s_barrier();  // (B)
  }
#undef STAGE256

#pragma unroll
  for (int mi = 0; mi < 8; mi++) {
#pragma unroll
    for (int ni = 0; ni < 4; ni++) {
      long col = nBase + wn * 64 + ni * 16 + lm;
      long rw0 = mBase + wm * 128 + mi * 16 + quad * 4;
#pragma unroll
      for (int r = 0; r < 4; r++) {
        float y = acc[mi][ni][r];
        long row = rw0 + r;
        long off = row * (long)N + col;
        if constexpr (EPI == 0) {
          ((float*)Cp)[off] = y;
        } else if constexpr (EPI == 3) {
          ((unsigned short*)Cp)[off] = f2bf(y / (1.f + __expf(-y)));
        } else if constexpr (EPI == 5) {
          int bb = (int)(row >> 11), t = (int)(row & 2047);
          int n = t >> 5, tt = t & 31;
          int h = (int)(col >> 6), kk = (int)(col & 63);
          long c = ((long)(bb * 32 + h)) * 64 + n;
          ((unsigned short*)Cp)[c * 6144 + slot + tt * 64 + kk] = f2bf(y);
        }
      }
    }
  }
}

// ---------------- weight convert / transpose ----------------
__global__ __launch_bounds__(256) void k_convert(const float* __restrict__ s,
                                                 unsigned short* __restrict__ d, int n4)
{
  int i = blockIdx.x * 256 + threadIdx.x;
  if (i >= n4) return;
  float4 v = ((const float4*)s)[i];
  short4 o;
  o.x = (short)f2bf(v.x); o.y = (short)f2bf(v.y);
  o.z = (short)f2bf(v.z); o.w = (short)f2bf(v.w);
  ((short4*)d)[i] = o;
}

// src (R x C) f32 -> dst (C x R) bf16
__global__ __launch_bounds__(256) void k_transpose(const float* __restrict__ s,
                                                   unsigned short* __restrict__ d, int R, int C)
{
  int i = blockIdx.x * 256 + threadIdx.x;
  if (i >= R * C) return;
  int r = i / C, c = i - r * C;
  d[(long)c * R + r] = f2bf(s[i]);
}

// ---------------- prep: xmix, xbf, dxbf (bf16), x_last out ------------------
// xbf/dxbf land in d_out scratch (dead until k_chunk rewrites it).
__global__ __launch_bounds__(256) void k_prep(const float* __restrict__ x,
                                              const float* __restrict__ shift,
                                              const float* __restrict__ maax,
                                              unsigned short* __restrict__ xmix,
                                              float* __restrict__ xlast,
                                              unsigned short* __restrict__ xbf,
                                              unsigned short* __restrict__ dxbf)
{
  int i = blockIdx.x * 256 + threadIdx.x; // over B*T*C/4
  int c4 = (i & 511) * 4;
  long bt = i >> 9;
  int t = (int)(bt & 2047);
  long b = bt >> 11;
  float4 xv = *(const float4*)&x[bt * 2048 + c4];
  float4 xp;
  if (t == 0) xp = *(const float4*)&shift[b * 2048 + c4];
  else        xp = *(const float4*)&x[(bt - 1) * 2048 + c4];
  float4 mx = *(const float4*)&maax[c4];
  short4 o;
  o.x = (short)f2bf(xv.x + (xp.x - xv.x) * mx.x);
  o.y = (short)f2bf(xv.y + (xp.y - xv.y) * mx.y);
  o.z = (short)f2bf(xv.z + (xp.z - xv.z) * mx.z);
  o.w = (short)f2bf(xv.w + (xp.w - xv.w) * mx.w);
  *(short4*)&xmix[bt * 2048 + c4] = o;
  short4 xo;
  xo.x = (short)f2bf(xv.x); xo.y = (short)f2bf(xv.y);
  xo.z = (short)f2bf(xv.z); xo.w = (short)f2bf(xv.w);
  *(short4*)&xbf[bt * 2048 + c4] = xo;
  short4 dxo;
  dxo.x = (short)f2bf(xp.x - xv.x); dxo.y = (short)f2bf(xp.y - xv.y);
  dxo.z = (short)f2bf(xp.z - xv.z); dxo.w = (short)f2bf(xp.w - xv.w);
  *(short4*)&dxbf[bt * 2048 + c4] = dxo;
  if (t == 2047) *(float4*)&xlast[b * 2048 + c4] = xv;
}

// ---------------- single-feature mix: m = xxx_f @ w2t_f; x_f out -----------
// reads bf16 xbf/dxbf (half the bytes of f32 x; no t==0 branch)
__global__ __launch_bounds__(256) void k_mix1(
    const unsigned short* __restrict__ xxx, const unsigned short* __restrict__ w2t,
    const unsigned short* __restrict__ xbf, const unsigned short* __restrict__ dxbf,
    const float* __restrict__ maa, unsigned short* __restrict__ xout, int f)
{
  __shared__ __align__(16) unsigned short As[128 * 32];
  __shared__ __align__(16) unsigned short Bs[128 * 32];
  const int tid = threadIdx.x;
  const int l = tid & 63, w = tid >> 6;
  const int wm = w & 1, wn = w >> 1;
  const int lm = l & 15, quad = l >> 4;
  const long mBase = (long)blockIdx.y * 128;
  const long nBase = (long)blockIdx.x * 128;
  const int row = tid >> 2, ch = tid & 3;
#pragma unroll
  for (int rr = 0; rr < 128; rr += 64) {
    int r = rr + row;
    *(int4*)&As[r * 32 + ch * 8] =
        *(const int4*)&xxx[(mBase + r) * 160 + f * 32 + ch * 8];
    *(int4*)&Bs[r * 32 + ch * 8] =
        *(const int4*)&w2t[((long)f * 2048 + nBase + r) * 32 + ch * 8];
  }
  __syncthreads();
  f32x4 zero = {0.f, 0.f, 0.f, 0.f};
  f32x4 acc[4][4];
#pragma unroll
  for (int i = 0; i < 4; i++)
#pragma unroll
    for (int j = 0; j < 4; j++) acc[i][j] = zero;
  bf16x8 af[4], bq[4];
#pragma unroll
  for (int i = 0; i < 4; i++)
    af[i] = *(const bf16x8*)&As[(wm * 64 + i * 16 + lm) * 32 + quad * 8];
#pragma unroll
  for (int i = 0; i < 4; i++)
    bq[i] = *(const bf16x8*)&Bs[(wn * 64 + i * 16 + lm) * 32 + quad * 8];
#pragma unroll
  for (int mi = 0; mi < 4; mi++)
#pragma unroll
    for (int ni = 0; ni < 4; ni++)
      acc[mi][ni] = __builtin_amdgcn_mfma_f32_16x16x32_bf16(af[mi], bq[ni], acc[mi][ni], 0, 0, 0);

#pragma unroll
  for (int mi = 0; mi < 4; mi++) {
#pragma unroll
    for (int ni = 0; ni < 4; ni++) {
      long col = nBase + wn * 64 + ni * 16 + lm;
#pragma unroll
      for (int r = 0; r < 4; r++) {
        long rg = mBase + wm * 64 + mi * 16 + quad * 4 + r;
        long off = rg * 2048 + col;
        float xval = bf2f(xbf[off]);
        float dxv = bf2f(dxbf[off]);
        float res = xval + dxv * (maa[col] + acc[mi][ni][r]);
        xout[off] = f2bf(res);
      }
    }
  }
}

// ---------------- per-chunk rwkv (intra), MFMA + split-bf16 -----------------
// recs: per chunk c, 6144 bf16: [r(2048) | k(2048) | v(2048)]  (t*64+kk)
// In place: wkv (4096) overwrites r+k; r*w_intra (2048) overwrites v.
// amat and k*w_inter kept at ~f32 precision via hi/lo bf16 split operands.
// __launch_bounds__(256,4): cap VGPR at 128 -> 4 blocks/CU (R5 had 140 VGPR,
// 3 blocks/CU, 11.5% occupancy, HBM 775 GB/s -> latency-bound).
__global__ __launch_bounds__(256, 4) void k_chunk(
    unsigned short* __restrict__ recs, const _Float16* __restrict__ wl,
    const float* __restrict__ u, float* __restrict__ outw,
    float* __restrict__ wsb)
{
  const int chunk = blockIdx.x;              // ((b*32 + h)*64 + n)
  const int n = chunk & 63, bh = chunk >> 6;
  const int h = bh & 31, b = bh >> 5;
  const int tid = threadIdx.x;
  const int lane = tid & 63, w = tid >> 6;
  const int lm = lane & 15, quad = lane >> 4;
  const long rec = (long)chunk * 6144;
  const long tbase = ((long)(b * 2048 + n * 32)) * 2048 + h * 64;

  __shared__ float rdec[32][68];              // [t][channel 0..63] + 4 pad
  __shared__ float kdec[32][68];
  __shared__ float ssum[4][64];
  __shared__ float offr[64];
  __shared__ float diagr[32];
  __shared__ __align__(16) unsigned short amatH[32][40];  // bf16 hi A [t][s]
  __shared__ __align__(16) unsigned short amatL[32][40];  // bf16 lo
  __shared__ __align__(16) unsigned short vcT[64][40];    // bf16 B [v][t]
  __shared__ __align__(16) unsigned short kwH[64][40];    // bf16 hi A [k][t]
  __shared__ __align__(16) unsigned short kwL[64][40];    // bf16 lo

  // ---- phase 1: loads + wlog + local prefix + vcT ----
  float rv[8], kv[8], wlog[8], cum[8];
#pragma unroll
  for (int j = 0; j < 8; j++) {
    int t = w * 8 + j;
    long g = rec + t * 64 + lane;
    rv[j] = bf2f(recs[g]);
    kv[j] = bf2f(recs[g + 2048]);
    wlog[j] = (float)wl[tbase + (long)t * 2048 + lane];
  }
  {
    float run = 0.f;
#pragma unroll
    for (int j = 0; j < 8; j++) { run += wlog[j]; cum[j] = run; }
    ssum[w][lane] = run;
  }
#pragma unroll
  for (int jp = 0; jp < 4; jp++) {
    int t0 = w * 8 + jp * 2;
    float v0 = bf2f(recs[rec + (t0) * 64 + lane + 4096]);
    float v1 = bf2f(recs[rec + (t0 + 1) * 64 + lane + 4096]);
    *(unsigned int*)&vcT[lane][t0] = packbf(v0, v1);
  }
  __syncthreads();  // b1: ssum + vcT visible

  float off = 0.f, tot = 0.f;
#pragma unroll
  for (int w2 = 0; w2 < 4; w2++) {
    float s2 = ssum[w2][lane];
    tot += s2;
    if (w2 < w) off += s2;
  }
#pragma unroll
  for (int j = 0; j < 8; j++) cum[j] += off;
  if (w == 1) offr[lane] = cum[7];            // wcum at t=15
  if (w == 0) wsb[(long)chunk * 64 + lane] = __expf(tot);
  __syncthreads();  // b2: offr visible

  const float offv = offr[lane];
  const float uval = u[h * 64 + lane];
#pragma unroll
  for (int jp = 0; jp < 4; jp++) {
    unsigned short h2[2], l2[2];
#pragma unroll
    for (int p = 0; p < 2; p++) {
      int j = jp * 2 + p;
      int t = w * 8 + j;
      float cw = cum[j];
      float sh = cw - wlog[j];
      rdec[t][lane] = rv[j] * __expf(sh - offv);
      kdec[t][lane] = kv[j] * __expf(offv - cw);
      float kw_ = kv[j] * __expf(tot - cw);    // k * w_inter (f32)
      h2[p] = f2bf(kw_);
      l2[p] = f2bf(kw_ - bf2f(h2[p]));
      recs[rec + 4096 + t * 64 + lane] = f2bf(rv[j] * __expf(sh));
    }
    *(unsigned int*)&kwH[lane][w * 8 + jp * 2] = (unsigned int)h2[0] | ((unsigned int)h2[1] << 16);
    *(unsigned int*)&kwL[lane][w * 8 + jp * 2] = (unsigned int)l2[0] | ((unsigned int)l2[1] << 16);
  }
  // diagonal partials: diag[t] = sum_k r*u*k
#pragma unroll
  for (int j = 0; j < 8; j++) {
    float d = rv[j] * uval * kv[j];
#pragma unroll
    for (int m = 32; m; m >>= 1) d += __shfl_xor(d, m, 64);
    if (lane == 0) diagr[w * 8 + j] = d;
  }
  __syncthreads();  // b3: rdec/kdec/kwH/kwL/diagr visible

  // ---- phase 2: amat f32 (vectorized b128), masked -> hi/lo bf16 LDS ----
  {
    const int t0 = (tid >> 4) * 2;            // 0..30 even
    const int sA = tid & 15;                  // s in {sA, sA+16}
    float a00 = 0, a01 = 0, a10 = 0, a11 = 0;
#pragma unroll
    for (int kk = 0; kk < 64; kk += 4) {
      float4 r0 = *(const float4*)&rdec[t0][kk];
      float4 r1 = *(const float4*)&rdec[t0 + 1][kk];
      float4 c0 = *(const float4*)&kdec[sA][kk];
      float4 c1 = *(const float4*)&kdec[sA + 16][kk];
      a00 += r0.x * c0.x + r0.y * c0.y + r0.z * c0.z + r0.w * c0.w;
      a01 += r0.x * c1.x + r0.y * c1.y + r0.z * c1.z + r0.w * c1.w;
      a10 += r1.x * c0.x + r1.y * c0.y + r1.z * c0.z + r1.w * c0.w;
      a11 += r1.x * c1.x + r1.y * c1.y + r1.z * c1.z + r1.w * c1.w;
    }
    const int sB = sA + 16;
    float m00 = sA < t0 ? a00 : (sA == t0 ? diagr[t0] : 0.f);
    float m01 = sB < t0 ? a01 : (sB == t0 ? diagr[t0] : 0.f);
    float m10 = sA < t0 + 1 ? a10 : (sA == t0 + 1 ? diagr[t0 + 1] : 0.f);
    float m11 = sB < t0 + 1 ? a11 : (sB == t0 + 1 ? diagr[t0 + 1] : 0.f);
    unsigned short h00 = f2bf(m00), h01 = f2bf(m01), h10 = f2bf(m10), h11 = f2bf(m11);
    amatH[t0][sA] = h00;     amatL[t0][sA] = f2bf(m00 - bf2f(h00));
    amatH[t0][sB] = h01;     amatL[t0][sB] = f2bf(m01 - bf2f(h01));
    amatH[t0 + 1][sA] = h10; amatL[t0 + 1][sA] = f2bf(m10 - bf2f(h10));
    amatH[t0 + 1][sB] = h11; amatL[t0 + 1][sB] = f2bf(m11 - bf2f(h11));
  }
  __syncthreads();  // b4: amatH/L visible

  // ---- phase 3: MFMA (split hi/lo). out_intra + wkv ----
  {
    bf16x8 bv[4];
#pragma unroll
    for (int ni = 0; ni < 4; ni++)
      bv[ni] = *(const bf16x8*)&vcT[ni * 16 + lm][quad * 8];

    const int ti = w >> 1;
    bf16x8 avh = *(const bf16x8*)&amatH[ti * 16 + lm][quad * 8];
    bf16x8 avl = *(const bf16x8*)&amatL[ti * 16 + lm][quad * 8];
    bf16x8 akh = *(const bf16x8*)&kwH[w * 16 + lm][quad * 8];
    bf16x8 akl = *(const bf16x8*)&kwL[w * 16 + lm][quad * 8];

    f32x4 zero = {0.f, 0.f, 0.f, 0.f};
    f32x4 oc0 = zero, oc1 = zero;
    const int nA = (w & 1) * 2;
    oc0 = __builtin_amdgcn_mfma_f32_16x16x32_bf16(avh, bv[nA], oc0, 0, 0, 0);
    oc0 = __builtin_amdgcn_mfma_f32_16x16x32_bf16(avl, bv[nA], oc0, 0, 0, 0);
    oc1 = __builtin_amdgcn_mfma_f32_16x16x32_bf16(avh, bv[nA + 1], oc1, 0, 0, 0);
    oc1 = __builtin_amdgcn_mfma_f32_16x16x32_bf16(avl, bv[nA + 1], oc1, 0, 0, 0);
    f32x4 kc[4];
#pragma unroll
    for (int ni = 0; ni < 4; ni++) {
      kc[ni] = zero;
      kc[ni] = __builtin_amdgcn_mfma_f32_16x16x32_bf16(akh, bv[ni], kc[ni], 0, 0, 0);
      kc[ni] = __builtin_amdgcn_mfma_f32_16x16x32_bf16(akl, bv[ni], kc[ni], 0, 0, 0);
    }

    // out_intra epilogue: direct store (k_inter adds later)
#pragma unroll
    for (int r = 0; r < 4; r++) {
      int t = ti * 16 + quad * 4 + r;
      outw[tbase + (long)t * 2048 + nA * 16 + lm] = oc0[r];
      outw[tbase + (long)t * 2048 + (nA + 1) * 16 + lm] = oc1[r];
    }
    // wkv epilogue -> overwrites r+k slots
#pragma unroll
    for (int ni = 0; ni < 4; ni++)
#pragma unroll
      for (int r = 0; r < 4; r++) {
        int kk = w * 16 + quad * 4 + r;
        recs[rec + kk * 64 + ni * 16 + lm] = f2bf(kc[ni][r]);
      }
  }
}

// ---------------- sequential scan over chunks (in-place wkv->state) --------
// widened: 1024 blocks (8 k-groups of 8 rows), 2 accum/thread
__global__ __launch_bounds__(256) void k_scan(unsigned short* __restrict__ recs,
                                              const float* __restrict__ wsb,
                                              const float* __restrict__ kv0,
                                              float* __restrict__ finalst)
{
  const int bh = blockIdx.x >> 3;   // 128 (b,h)
  const int kq = blockIdx.x & 7;    // 8 groups of 8 k-rows
  const int tid = threadIdx.x;
  float st[2];
  const long base = (long)bh * 4096 + kq * 512;
#pragma unroll
  for (int j = 0; j < 2; j++) st[j] = kv0[base + j * 256 + tid];
  for (int n = 0; n < 64; n++) {
    const long cb = ((long)bh * 64 + n) * 6144 + kq * 512;
    const long wb = ((long)bh * 64 + n) * 64 + kq * 8;
#pragma unroll
    for (int j = 0; j < 2; j++) {
      int i = j * 256 + tid;
      unsigned short* p = &recs[cb + i];
      float wv = bf2f(*p);
      *p = f2bf(st[j]);                       // pre-update state
      st[j] = st[j] * wsb[wb + (i >> 6)] + wv;
    }
  }
#pragma unroll
  for (int j = 0; j < 2; j++) finalst[base + j * 256 + tid] = st[j];
}

// ---------------- inter-chunk contribution (MFMA, exact bf16 math) --------
// out[t][v] += sum_k rw[t][k] * st[k][v];  rw, st already bf16 in recs.
__global__ __launch_bounds__(256) void k_inter(const unsigned short* __restrict__ recs,
                                               float* __restrict__ outw)
{
  const int chunk = blockIdx.x;
  const int n = chunk & 63, bh = chunk >> 6;
  const int h = bh & 31, b = bh >> 5;
  const int tid = threadIdx.x;
  const int lane = tid & 63, w = tid >> 6;
  const int lm = lane & 15, quad = lane >> 4;
  const long rec = (long)chunk * 6144;
  const long tbase = ((long)(b * 2048 + n * 32)) * 2048 + h * 64;

  __shared__ __align__(16) unsigned short stT[64][72];  // B [v][k], 144B rows
  __shared__ __align__(16) unsigned short rwb[32][72];  // A [t][k]

  // rw: 2048 bf16, vector load + aligned LDS write
  {
    int4 rwv = *(const int4*)&recs[rec + 4096 + tid * 8];
    *(int4*)&rwb[tid >> 3][(tid & 7) * 8] = rwv;
  }
  // st: 4096 bf16, transpose into stT
  for (int ii = tid; ii < 4096; ii += 256)
    stT[ii & 63][ii >> 6] = recs[rec + ii];
  __syncthreads();

  // wave w: t-tile mi = w>>1, n-tiles {nset*2, nset*2+1}
  const int mi = w >> 1, nset = w & 1;
  bf16x8 aA[2], bB[2][2];
#pragma unroll
  for (int kk = 0; kk < 2; kk++) {
    aA[kk] = *(const bf16x8*)&rwb[mi * 16 + lm][kk * 32 + quad * 8];
#pragma unroll
    for (int p = 0; p < 2; p++)
      bB[p][kk] = *(const bf16x8*)&stT[(nset * 2 + p) * 16 + lm][kk * 32 + quad * 8];
  }
  f32x4 zero = {0.f, 0.f, 0.f, 0.f};
  f32x4 oc[2] = {zero, zero};
#pragma unroll
  for (int kk = 0; kk < 2; kk++) {
    oc[0] = __builtin_amdgcn_mfma_f32_16x16x32_bf16(aA[kk], bB[0][kk], oc[0], 0, 0, 0);
    oc[1] = __builtin_amdgcn_mfma_f32_16x16x32_bf16(aA[kk], bB[1][kk], oc[1], 0, 0, 0);
  }
#pragma unroll
  for (int p = 0; p < 2; p++) {
    int v = (nset * 2 + p) * 16 + lm;
#pragma unroll
    for (int r = 0; r < 4; r++) {
      int t = mi * 16 + quad * 4 + r;
      outw[tbase + (long)t * 2048 + v] += oc[p][r];
    }
  }
}

// ---------------- groupnorm(64) * g -> bf16 A for Wo GEMM ------------------
__global__ __launch_bounds__(256) void k_gnorm(const float* __restrict__ outw,
                                               const unsigned short* __restrict__ gb,
                                               const float* __restrict__ gnw,
                                               const float* __restrict__ gnb,
                                               unsigned short* __restrict__ aout)
{
  const int gid = blockIdx.x * 4 + (threadIdx.x >> 6); // over B*T*H
  const int lane = threadIdx.x & 63;
  const long bt = gid >> 5;
  const int h = gid & 31;
  const int c = h * 64 + lane;
  const long off = bt * 2048 + c;
  float y = outw[off];
  float s = y, sq = y * y;
#pragma unroll
  for (int m = 32; m; m >>= 1) {
    s += __shfl_xor(s, m, 64);
    sq += __shfl_xor(sq, m, 64);
  }
  float mu = s * (1.f / 64.f);
  float var = sq * (1.f / 64.f) - mu * mu;
  float nrm = (y - mu) * rsqrtf(var + 6.4e-4f);
  float o = (nrm * gnw[c] + gnb[c]) * bf2f(gb[off]);
  aout[off] = f2bf(o);
}

// ---------------- host ------------------------------------------------------
extern "C" void kernel_launch(void* const* d_in, const int* in_sizes, int n_in,
                              void* d_out, int out_size, void* d_ws, size_t ws_size,
                              hipStream_t stream)
{
  const float* x     = (const float*)d_in[0];
  const float* shift = (const float*)d_in[1];
  const float* kv0   = (const float*)d_in[2];
  const float* maax  = (const float*)d_in[3];
  const float* maaw  = (const float*)d_in[4];
  const float* maak  = (const float*)d_in[5];
  const float* maav  = (const float*)d_in[6];
  const float* maar  = (const float*)d_in[7];
  const float* maag  = (const float*)d_in[8];
  const float* w1    = (const float*)d_in[9];
  const float* w2    = (const float*)d_in[10];
  const float* tdec  = (const float*)d_in[11];
  const float* tdw1  = (const float*)d_in[12];
  const float* tdw2  = (const float*)d_in[13];
  const float* u     = (const float*)d_in[14];
  const float* Wr    = (const float*)d_in[15];
  const float* Wk    = (const float*)d_in[16];
  const float* Wv    = (const float*)d_in[17];
  const float* Wg    = (const float*)d_in[18];
  const float* Wo    = (const float*)d_in[19];
  const float* gnw   = (const float*)d_in[20];
  const float* gnb   = (const float*)d_in[21];

  char* ws = (char*)d_ws;
  const size_t MB = 1048576;
  unsigned short* WbfR  = (unsigned short*)(ws + 0 * MB);
  unsigned short* WbfK  = (unsigned short*)(ws + 8 * MB);
  unsigned short* WbfV  = (unsigned short*)(ws + 16 * MB);
  unsigned short* WbfG  = (unsigned short*)(ws + 24 * MB);
  unsigned short* WbfO  = (unsigned short*)(ws + 32 * MB);
  unsigned short* w2tb  = (unsigned short*)(ws + 40 * MB);
  unsigned short* w1t   = (unsigned short*)(ws + 40 * MB + 655360);
  unsigned short* tdw1t = (unsigned short*)(ws + 40 * MB + 1310720);
  unsigned short* tdw2t = (unsigned short*)(ws + 40 * MB + 1572864);
  unsigned short* xxxb  = (unsigned short*)(ws + 40 * MB + 1835008);
  unsigned short* t1b   = (unsigned short*)(ws + 40 * MB + 4456448);
  float*          wsb   = (float*)(ws + 40 * MB + 5505024);
  unsigned short* xmixb = (unsigned short*)(ws + 48 * MB);
  _Float16*       wlb   = (_Float16*)(ws + 48 * MB);
  unsigned short* x1b   = (unsigned short*)(ws + 80 * MB);
  unsigned short* aob   = (unsigned short*)(ws + 80 * MB);
  unsigned short* recs  = (unsigned short*)(ws + 112 * MB);
  unsigned short* gbuf  = recs;

  float* outp    = (float*)d_out;
  float* xlast   = outp + 16777216;
  float* finalst = outp + 16777216 + 8192;
  // d_out scratch (dead until k_chunk): xbf 33.5MB + dxbf 33.5MB
  unsigned short* xbfb  = (unsigned short*)outp;
  unsigned short* dxbfb = xbfb + 16777216;

  // weights -> bf16
  k_convert<<<4096, 256, 0, stream>>>(Wr, WbfR, 1048576);
  k_convert<<<4096, 256, 0, stream>>>(Wk, WbfK, 1048576);
  k_convert<<<4096, 256, 0, stream>>>(Wv, WbfV, 1048576);
  k_convert<<<4096, 256, 0, stream>>>(Wg, WbfG, 1048576);
  k_convert<<<4096, 256, 0, stream>>>(Wo, WbfO, 1048576);
  // transposes
  k_transpose<<<1280, 256, 0, stream>>>(w1, w1t, 2048, 160);
  k_transpose<<<512, 256, 0, stream>>>(tdw1, tdw1t, 2048, 64);
  k_transpose<<<512, 256, 0, stream>>>(tdw2, tdw2t, 64, 2048);
  for (int f = 0; f < 5; f++)
    k_transpose<<<256, 256, 0, stream>>>(w2 + (long)f * 65536, w2tb + (long)f * 65536, 32, 2048);

  // prep + x_last + xbf/dxbf (into d_out scratch)
  k_prep<<<16384, 256, 0, stream>>>(x, shift, maax, xmixb, xlast, xbfb, dxbfb);
  // xxx = tanh(xmix @ w1^T)
  gemm_nt<2, true><<<dim3(2, 64), 256, 0, stream>>>(xmixb, w1t, xxxb, 8192, 160, 2048, nullptr, 0);

  // f=0 (w): mix -> decay chain -> wlog (f16, over dead xmixb)
  k_mix1<<<dim3(16, 64), 256, 0, stream>>>(xxxb, w2tb, xbfb, dxbfb, maaw, x1b, 0);
  gemm_nt<2, true><<<dim3(1, 64), 256, 0, stream>>>(x1b, tdw1t, t1b, 8192, 64, 2048, nullptr, 0);
  gemm_nt<4, false><<<dim3(16, 64), 256, 0, stream>>>(t1b, tdw2t, wlb, 8192, 2048, 64, tdec, 0);
  // f=1 (k)
  k_mix1<<<dim3(16, 64), 256, 0, stream>>>(xxxb, w2tb, xbfb, dxbfb, maak, x1b, 1);
  gemm256_nt<5><<<dim3(8, 32), 512, 0, stream>>>(x1b, WbfK, recs, 8192, 2048, 2048, 2048);
  // f=2 (v)
  k_mix1<<<dim3(16, 64), 256, 0, stream>>>(xxxb, w2tb, xbfb, dxbfb, maav, x1b, 2);
  gemm256_nt<5><<<dim3(8, 32), 512, 0, stream>>>(x1b, WbfV, recs, 8192, 2048, 2048, 4096);
  // f=3 (r)
  k_mix1<<<dim3(16, 64), 256, 0, stream>>>(xxxb, w2tb, xbfb, dxbfb, maar, x1b, 3);
  gemm256_nt<5><<<dim3(8, 32), 512, 0, stream>>>(x1b, WbfR, recs, 8192, 2048, 2048, 0);
  // f=4 (g): x1b holds xg until the G GEMM below
  k_mix1<<<dim3(16, 64), 256, 0, stream>>>(xxxb, w2tb, xbfb, dxbfb, maag, x1b, 4);

  // chunked rwkv (outw accumulated f32 directly in d_out; overwrites scratch)
  k_chunk<<<8192, 256, 0, stream>>>(recs, wlb, u, outp, wsb);
  k_scan<<<1024, 256, 0, stream>>>(recs, wsb, kv0, finalst);
  k_inter<<<8192, 256, 0, stream>>>(recs, outp);

  // g = silu(xg @ Wg^T) (records dead -> gbuf), then groupnorm*g, then Wo
  gemm256_nt<3><<<dim3(8, 32), 512, 0, stream>>>(x1b, WbfG, gbuf, 8192, 2048, 2048, 0);
  k_gnorm<<<65536, 256, 0, stream>>>(outp, gbuf, gnw, gnb, aob);
  gemm256_nt<0><<<dim3(8, 32), 512, 0, stream>>>(aob, WbfO, outp, 8192, 2048, 2048, 0);
}

// Round 8
// 1133.234 us; speedup vs baseline: 1.3187x; 1.3187x over previous
//
#include <hip/hip_runtime.h>
#include <stdint.h>
#include <math.h>

// RWKV-6 TimeMix forward, MI355X gfx950.
// B=4 T=2048 C=2048 H=32 K=64, chunk len 32, N=64 chunks, M=B*T=8192.
// Workspace footprint: 208 MiB (phase-disjoint aliasing; see layout below).

typedef __attribute__((ext_vector_type(8))) short bf16x8;
typedef __attribute__((ext_vector_type(4))) float f32x4;

#define AS1(p) ((const __attribute__((address_space(1))) void*)(p))
#define AS3(p) ((__attribute__((address_space(3))) void*)(p))

__device__ __forceinline__ unsigned short f2bf(float f) {
  unsigned int u = __builtin_bit_cast(unsigned int, f);
  u += 0x7fffu + ((u >> 16) & 1u);
  return (unsigned short)(u >> 16);
}
__device__ __forceinline__ float bf2f(unsigned short s) {
  unsigned int u = ((unsigned int)s) << 16;
  return __builtin_bit_cast(float, u);
}

// ---------------- generic NT GEMM: C[m,n] = sum_k A[m,k]*B[n,k], bf16 in ----
// EPI: 0 f32 std, 2 tanh->bf16 std, 3 silu->bf16 std, 4 wlog->f16 std,
//      5 bf16 chunk-record (slot = 0 r, 2048 k, 4096 v)
template <int EPI, bool BOUNDS>
__global__ __launch_bounds__(256) void gemm_nt(
    const unsigned short* __restrict__ A, const unsigned short* __restrict__ B,
    void* __restrict__ Cp, int M, int N, int K, const float* __restrict__ evec,
    int slot)
{
  __shared__ __align__(16) unsigned short As[128 * 32];
  __shared__ __align__(16) unsigned short Bs[128 * 32];
  const int tid = threadIdx.x;
  const int l = tid & 63, w = tid >> 6;
  const int wm = w & 1, wn = w >> 1;
  const int lm = l & 15, quad = l >> 4;
  const long mBase = (long)blockIdx.y * 128;
  const long nBase = (long)blockIdx.x * 128;

  f32x4 acc[4][4];
  f32x4 zero = {0.f, 0.f, 0.f, 0.f};
#pragma unroll
  for (int i = 0; i < 4; i++)
#pragma unroll
    for (int j = 0; j < 4; j++) acc[i][j] = zero;

  for (int k0 = 0; k0 < K; k0 += 32) {
    if (!BOUNDS) {
      const int r0 = w * 32;
      const int lr = l >> 2, lc = l & 3;
      const unsigned short* gA = A + (mBase + r0 + lr) * (long)K + k0 + lc * 8;
      __builtin_amdgcn_global_load_lds(AS1(gA), AS3(&As[r0 * 32]), 16, 0, 0);
      const unsigned short* gA2 = gA + 16 * (long)K;
      __builtin_amdgcn_global_load_lds(AS1(gA2), AS3(&As[(r0 + 16) * 32]), 16, 0, 0);
      const unsigned short* gB = B + (nBase + r0 + lr) * (long)K + k0 + lc * 8;
      __builtin_amdgcn_global_load_lds(AS1(gB), AS3(&Bs[r0 * 32]), 16, 0, 0);
      const unsigned short* gB2 = gB + 16 * (long)K;
      __builtin_amdgcn_global_load_lds(AS1(gB2), AS3(&Bs[(r0 + 16) * 32]), 16, 0, 0);
    } else {
      const int row = tid >> 2, ch = tid & 3;
#pragma unroll
      for (int rr = 0; rr < 128; rr += 64) {
        int r = rr + row;
        *(int4*)&As[r * 32 + ch * 8] =
            *(const int4*)&A[(mBase + r) * (long)K + k0 + ch * 8];
        int4 bv = make_int4(0, 0, 0, 0);
        long nG = nBase + r;
        if (nG < N) bv = *(const int4*)&B[nG * (long)K + k0 + ch * 8];
        *(int4*)&Bs[r * 32 + ch * 8] = bv;
      }
    }
    __syncthreads();
    bf16x8 af[4], bq[4];
#pragma unroll
    for (int i = 0; i < 4; i++)
      af[i] = *(const bf16x8*)&As[(wm * 64 + i * 16 + lm) * 32 + quad * 8];
#pragma unroll
    for (int i = 0; i < 4; i++)
      bq[i] = *(const bf16x8*)&Bs[(wn * 64 + i * 16 + lm) * 32 + quad * 8];
#pragma unroll
    for (int mi = 0; mi < 4; mi++)
#pragma unroll
      for (int ni = 0; ni < 4; ni++)
        acc[mi][ni] = __builtin_amdgcn_mfma_f32_16x16x32_bf16(af[mi], bq[ni], acc[mi][ni], 0, 0, 0);
    __syncthreads();
  }

#pragma unroll
  for (int mi = 0; mi < 4; mi++) {
#pragma unroll
    for (int ni = 0; ni < 4; ni++) {
      long col = nBase + wn * 64 + ni * 16 + lm;
      if (BOUNDS && col >= N) continue;
      long rw0 = mBase + wm * 64 + mi * 16 + quad * 4;
#pragma unroll
      for (int r = 0; r < 4; r++) {
        float y = acc[mi][ni][r];
        long row = rw0 + r;
        long off = row * (long)N + col;
        if constexpr (EPI == 0) {
          ((float*)Cp)[off] = y;
        } else if constexpr (EPI == 2) {
          ((unsigned short*)Cp)[off] = f2bf(tanhf(y));
        } else if constexpr (EPI == 3) {
          ((unsigned short*)Cp)[off] = f2bf(y / (1.f + __expf(-y)));
        } else if constexpr (EPI == 4) {
          float wv = evec[col] + y;
          ((_Float16*)Cp)[off] = (_Float16)fmaxf(-__expf(wv), -5.2983174f);
        } else if constexpr (EPI == 5) {
          int b = (int)(row >> 11), t = (int)(row & 2047);
          int n = t >> 5, tt = t & 31;
          int h = (int)(col >> 6), kk = (int)(col & 63);
          long c = ((long)(b * 32 + h)) * 64 + n;
          ((unsigned short*)Cp)[c * 6144 + slot + tt * 64 + kk] = f2bf(y);
        }
      }
    }
  }
}

// ---------------- 256x256 deep-pipelined NT GEMM (big shapes only) ----------
// Requirements: M%256==0, N%256==0, K%64==0, K>=128.
template <int EPI>
__global__ __launch_bounds__(512, 1) void gemm256_nt(
    const unsigned short* __restrict__ A, const unsigned short* __restrict__ B,
    void* __restrict__ Cp, int M, int N, int K, int slot)
{
  __shared__ __align__(16) unsigned short As2[2][16384];
  __shared__ __align__(16) unsigned short Bs2[2][16384];
  const int tid = threadIdx.x;
  const int l = tid & 63;
  const int w = tid >> 6;
  const int wm = w >> 2, wn = w & 3;
  const int lm = l & 15, quad = l >> 4;
  const long mBase = (long)blockIdx.y * 256;
  const long nBase = (long)blockIdx.x * 256;
  const int NT = K >> 6;

  const int r0 = tid >> 3;
  const int csw = (tid & 7) ^ (r0 & 7);
  const int ldsOff = (tid & ~63) * 8;
  const unsigned short* ga0 = A + (mBase + r0) * (long)K + csw * 8;
  const unsigned short* gb0 = B + (nBase + r0) * (long)K + csw * 8;

  f32x4 acc[8][4];
  f32x4 zero = {0.f, 0.f, 0.f, 0.f};
#pragma unroll
  for (int i = 0; i < 8; i++)
#pragma unroll
    for (int j = 0; j < 4; j++) acc[i][j] = zero;

#define STAGE256(kt_)                                                          \
  {                                                                            \
    const int _b = (kt_) & 1;                                                  \
    const unsigned short* _ga = ga0 + (long)(kt_) * 64;                        \
    const unsigned short* _gb = gb0 + (long)(kt_) * 64;                        \
    __builtin_amdgcn_global_load_lds(AS1(_ga), AS3(&As2[_b][ldsOff]), 16, 0, 0);              \
    __builtin_amdgcn_global_load_lds(AS1(_gb), AS3(&Bs2[_b][ldsOff]), 16, 0, 0);              \
    __builtin_amdgcn_global_load_lds(AS1(_ga + (long)64 * K), AS3(&As2[_b][4096 + ldsOff]), 16, 0, 0);  \
    __builtin_amdgcn_global_load_lds(AS1(_gb + (long)64 * K), AS3(&Bs2[_b][4096 + ldsOff]), 16, 0, 0);  \
    __builtin_amdgcn_global_load_lds(AS1(_ga + (long)128 * K), AS3(&As2[_b][8192 + ldsOff]), 16, 0, 0); \
    __builtin_amdgcn_global_load_lds(AS1(_gb + (long)128 * K), AS3(&Bs2[_b][8192 + ldsOff]), 16, 0, 0); \
    __builtin_amdgcn_global_load_lds(AS1(_ga + (long)192 * K), AS3(&As2[_b][12288 + ldsOff]), 16, 0, 0);\
    __builtin_amdgcn_global_load_lds(AS1(_gb + (long)192 * K), AS3(&Bs2[_b][12288 + ldsOff]), 16, 0, 0);\
  }

  STAGE256(0);
  STAGE256(1);
  asm volatile("s_waitcnt vmcnt(8)" ::: "memory");
  __builtin_amdgcn_s_barrier();

  const int q0 = (quad ^ (lm & 7)) * 8;
  const int rA = (wm * 128 + lm) * 64;
  const int rB = (wn * 64 + lm) * 64;

  for (int kt = 0; kt < NT; ++kt) {
    const int b = kt & 1;
    bf16x8 af[8][2], bq[4][2];
#pragma unroll
    for (int fm = 0; fm < 8; fm++)
      af[fm][0] = *(const bf16x8*)&As2[b][rA + fm * 1024 + q0];
#pragma unroll
    for (int fn = 0; fn < 4; fn++)
      bq[fn][0] = *(const bf16x8*)&Bs2[b][rB + fn * 1024 + q0];
#pragma unroll
    for (int fm = 0; fm < 8; fm++)
      af[fm][1] = *(const bf16x8*)&As2[b][rA + fm * 1024 + (q0 ^ 32)];
#pragma unroll
    for (int fn = 0; fn < 4; fn++)
      bq[fn][1] = *(const bf16x8*)&Bs2[b][rB + fn * 1024 + (q0 ^ 32)];

    __builtin_amdgcn_s_setprio(1);
#pragma unroll
    for (int fm = 0; fm < 8; fm++)
#pragma unroll
      for (int fn = 0; fn < 4; fn++)
        acc[fm][fn] = __builtin_amdgcn_mfma_f32_16x16x32_bf16(af[fm][0], bq[fn][0], acc[fm][fn], 0, 0, 0);
    __builtin_amdgcn_s_setprio(0);

    asm volatile("s_waitcnt lgkmcnt(0)" ::: "memory");
    __builtin_amdgcn_s_barrier();  // (A)
    if (kt + 2 < NT) STAGE256(kt + 2);

    __builtin_amdgcn_s_setprio(1);
#pragma unroll
    for (int fm = 0; fm < 8; fm++)
#pragma unroll
      for (int fn = 0; fn < 4; fn++)
        acc[fm][fn] = __builtin_amdgcn_mfma_f32_16x16x32_bf16(af[fm][1], bq[fn][1], acc[fm][fn], 0, 0, 0);
    __builtin_amdgcn_s_setprio(0);

    if (kt + 2 < NT) {
      asm volatile("s_waitcnt vmcnt(8)" ::: "memory");
    } else {
      asm volatile("s_waitcnt vmcnt(0)" ::: "memory");
    }
    __builtin_amdgcn_s_barrier();  // (B)
  }
#undef STAGE256

#pragma unroll
  for (int mi = 0; mi < 8; mi++) {
#pragma unroll
    for (int ni = 0; ni < 4; ni++) {
      long col = nBase + wn * 64 + ni * 16 + lm;
      long rw0 = mBase + wm * 128 + mi * 16 + quad * 4;
#pragma unroll
      for (int r = 0; r < 4; r++) {
        float y = acc[mi][ni][r];
        long row = rw0 + r;
        long off = row * (long)N + col;
        if constexpr (EPI == 0) {
          ((float*)Cp)[off] = y;
        } else if constexpr (EPI == 3) {
          ((unsigned short*)Cp)[off] = f2bf(y / (1.f + __expf(-y)));
        } else if constexpr (EPI == 5) {
          int bb = (int)(row >> 11), t = (int)(row & 2047);
          int n = t >> 5, tt = t & 31;
          int h = (int)(col >> 6), kk = (int)(col & 63);
          long c = ((long)(bb * 32 + h)) * 64 + n;
          ((unsigned short*)Cp)[c * 6144 + slot + tt * 64 + kk] = f2bf(y);
        }
      }
    }
  }
}

// ---------------- weight convert / transpose ----------------
__global__ __launch_bounds__(256) void k_convert(const float* __restrict__ s,
                                                 unsigned short* __restrict__ d, int n4)
{
  int i = blockIdx.x * 256 + threadIdx.x;
  if (i >= n4) return;
  float4 v = ((const float4*)s)[i];
  short4 o;
  o.x = (short)f2bf(v.x); o.y = (short)f2bf(v.y);
  o.z = (short)f2bf(v.z); o.w = (short)f2bf(v.w);
  ((short4*)d)[i] = o;
}

// src (R x C) f32 -> dst (C x R) bf16
__global__ __launch_bounds__(256) void k_transpose(const float* __restrict__ s,
                                                   unsigned short* __restrict__ d, int R, int C)
{
  int i = blockIdx.x * 256 + threadIdx.x;
  if (i >= R * C) return;
  int r = i / C, c = i - r * C;
  d[(long)c * R + r] = f2bf(s[i]);
}

// ---------------- prep: xmix = x + (xprev-x)*maa_x (bf16), x_last out -------
__global__ __launch_bounds__(256) void k_prep(const float* __restrict__ x,
                                              const float* __restrict__ shift,
                                              const float* __restrict__ maax,
                                              unsigned short* __restrict__ xmix,
                                              float* __restrict__ xlast)
{
  int i = blockIdx.x * 256 + threadIdx.x; // over B*T*C/4
  int c4 = (i & 511) * 4;
  long bt = i >> 9;
  int t = (int)(bt & 2047);
  long b = bt >> 11;
  float4 xv = *(const float4*)&x[bt * 2048 + c4];
  float4 xp;
  if (t == 0) xp = *(const float4*)&shift[b * 2048 + c4];
  else        xp = *(const float4*)&x[(bt - 1) * 2048 + c4];
  float4 mx = *(const float4*)&maax[c4];
  short4 o;
  o.x = (short)f2bf(xv.x + (xp.x - xv.x) * mx.x);
  o.y = (short)f2bf(xv.y + (xp.y - xv.y) * mx.y);
  o.z = (short)f2bf(xv.z + (xp.z - xv.z) * mx.z);
  o.w = (short)f2bf(xv.w + (xp.w - xv.w) * mx.w);
  *(short4*)&xmix[bt * 2048 + c4] = o;
  if (t == 2047) *(float4*)&xlast[b * 2048 + c4] = xv;
}

// ---------------- single-feature mix: m = xxx_f @ w2t_f; x_f out -----------
__global__ __launch_bounds__(256) void k_mix1(
    const unsigned short* __restrict__ xxx, const unsigned short* __restrict__ w2t,
    const float* __restrict__ x, const float* __restrict__ shift,
    const float* __restrict__ maa, unsigned short* __restrict__ xout, int f)
{
  __shared__ __align__(16) unsigned short As[128 * 32];
  __shared__ __align__(16) unsigned short Bs[128 * 32];
  const int tid = threadIdx.x;
  const int l = tid & 63, w = tid >> 6;
  const int wm = w & 1, wn = w >> 1;
  const int lm = l & 15, quad = l >> 4;
  const long mBase = (long)blockIdx.y * 128;
  const long nBase = (long)blockIdx.x * 128;
  const int row = tid >> 2, ch = tid & 3;
#pragma unroll
  for (int rr = 0; rr < 128; rr += 64) {
    int r = rr + row;
    *(int4*)&As[r * 32 + ch * 8] =
        *(const int4*)&xxx[(mBase + r) * 160 + f * 32 + ch * 8];
    *(int4*)&Bs[r * 32 + ch * 8] =
        *(const int4*)&w2t[((long)f * 2048 + nBase + r) * 32 + ch * 8];
  }
  __syncthreads();
  f32x4 zero = {0.f, 0.f, 0.f, 0.f};
  f32x4 acc[4][4];
#pragma unroll
  for (int i = 0; i < 4; i++)
#pragma unroll
    for (int j = 0; j < 4; j++) acc[i][j] = zero;
  bf16x8 af[4], bq[4];
#pragma unroll
  for (int i = 0; i < 4; i++)
    af[i] = *(const bf16x8*)&As[(wm * 64 + i * 16 + lm) * 32 + quad * 8];
#pragma unroll
  for (int i = 0; i < 4; i++)
    bq[i] = *(const bf16x8*)&Bs[(wn * 64 + i * 16 + lm) * 32 + quad * 8];
#pragma unroll
  for (int mi = 0; mi < 4; mi++)
#pragma unroll
    for (int ni = 0; ni < 4; ni++)
      acc[mi][ni] = __builtin_amdgcn_mfma_f32_16x16x32_bf16(af[mi], bq[ni], acc[mi][ni], 0, 0, 0);

#pragma unroll
  for (int mi = 0; mi < 4; mi++) {
#pragma unroll
    for (int ni = 0; ni < 4; ni++) {
      long col = nBase + wn * 64 + ni * 16 + lm;
#pragma unroll
      for (int r = 0; r < 4; r++) {
        long rg = mBase + wm * 64 + mi * 16 + quad * 4 + r;
        int t = (int)(rg & 2047);
        long b = rg >> 11;
        float xval = x[rg * 2048 + col];
        float xp = t ? x[(rg - 1) * 2048 + col] : shift[b * 2048 + col];
        float res = xval + (xp - xval) * (maa[col] + acc[mi][ni][r]);
        xout[rg * 2048 + col] = f2bf(res);
      }
    }
  }
}

// ---------------- per-chunk rwkv (intra) -----------------------------------
// recs: per chunk c, 6144 bf16: [r(2048) | k(2048) | v(2048)]  (t*64+kk)
// In place: wkv (4096) overwrites r+k; r*w_intra (2048) overwrites v.
// LDS stride 65 everywhere -> conflict-free access patterns.
// (R0 scalar version: 88 VGPR, measured 196-218 us. The MFMA rewrites
//  regressed: R5 306 us @140 VGPR latency-bound; R7 517 us @64 VGPR spill.)
__global__ __launch_bounds__(256) void k_chunk(
    unsigned short* __restrict__ recs, const _Float16* __restrict__ wl,
    const float* __restrict__ u, float* __restrict__ outw,
    float* __restrict__ wsb)
{
  const int chunk = blockIdx.x;              // ((b*32 + h)*64 + n)
  const int n = chunk & 63, bh = chunk >> 6;
  const int h = bh & 31, b = bh >> 5;
  const int tid = threadIdx.x;
  const int lane = tid & 63, wvid = tid >> 6;
  const long rec = (long)chunk * 6144;
  const long tbase = ((long)(b * 2048 + n * 32)) * 2048 + h * 64;

  __shared__ float vc[32][65];
  __shared__ float wcum[32][65];   // wlog -> cumsum in place -> later k*w_inter
  __shared__ float rdec[32][65];
  __shared__ float kdec[32][65];
  __shared__ float amat[32][33];
  __shared__ float wsk[64];

  // phase 1: wave wvid owns rows t = wvid+4j; kk = lane. r/k stay in regs.
  float rcr[8], kcr[8];
#pragma unroll
  for (int j = 0; j < 8; j++) {
    int t = wvid + 4 * j;
    long g = rec + t * 64 + lane;
    rcr[j] = bf2f(recs[g]);
    kcr[j] = bf2f(recs[g + 2048]);
    vc[t][lane] = bf2f(recs[g + 4096]);
    wcum[t][lane] = (float)wl[tbase + (long)t * 2048 + lane];
  }
  float uval = u[h * 64 + lane];
  __syncthreads();

  // cumsum along t, in place (64 threads; 2-way LDS aliasing = free)
  if (tid < 64) {
    float run = 0.f;
    for (int t = 0; t < 32; t++) { run += wcum[t][tid]; wcum[t][tid] = run; }
    wsk[tid] = run;
  }
  __syncthreads();

  // phase 2a: decays in regs (wcum still holds the cumsum)
  const float offv = wcum[15][lane];
  const float wsv = wsk[lane];
  float rdr[8], kdr[8], klr[8], rwir[8], dpart[8];
#pragma unroll
  for (int j = 0; j < 8; j++) {
    int t = wvid + 4 * j;
    float cw = wcum[t][lane];
    float sh = t ? wcum[t - 1][lane] : 0.f;
    rwir[j] = rcr[j] * __expf(sh);            // r * w_intra  (sh <= 0)
    rdr[j] = rcr[j] * __expf(sh - offv);
    kdr[j] = kcr[j] * __expf(offv - cw);
    klr[j] = kcr[j] * __expf(wsv - cw);       // k * w_inter
    dpart[j] = rcr[j] * uval * kcr[j];
  }
  __syncthreads();  // all wcum reads done before overwrite

  // phase 2b: publish to LDS/global
#pragma unroll
  for (int j = 0; j < 8; j++) {
    int t = wvid + 4 * j;
    rdec[t][lane] = rdr[j];
    kdec[t][lane] = kdr[j];
    wcum[t][lane] = klr[j];                    // now holds k*w_inter
    recs[rec + 4096 + t * 64 + lane] = f2bf(rwir[j]);
  }
  if (tid < 64) wsb[(long)chunk * 64 + tid] = __expf(wsk[tid]);
  __syncthreads();

  { // a[t][s] strictly lower triangular (diag filled later)
    const int t0 = (tid >> 4) * 2, s0 = (tid & 15) * 2;
    float a00 = 0, a01 = 0, a10 = 0, a11 = 0;
    for (int kk = 0; kk < 64; kk++) {
      float r0 = rdec[t0][kk], r1 = rdec[t0 + 1][kk];
      float c0 = kdec[s0][kk], c1 = kdec[s0 + 1][kk];
      a00 += r0 * c0; a01 += r0 * c1; a10 += r1 * c0; a11 += r1 * c1;
    }
    amat[t0][s0]         = (s0     < t0)     ? a00 : 0.f;
    amat[t0][s0 + 1]     = (s0 + 1 < t0)     ? a01 : 0.f;
    amat[t0 + 1][s0]     = (s0     < t0 + 1) ? a10 : 0.f;
    amat[t0 + 1][s0 + 1] = (s0 + 1 < t0 + 1) ? a11 : 0.f;
  }
  __syncthreads();
  // diagonal: wave-wide shuffle reduction of dpart (row t lives in wave wvid)
#pragma unroll
  for (int j = 0; j < 8; j++) {
    float d = dpart[j];
#pragma unroll
    for (int m = 32; m; m >>= 1) d += __shfl_xor(d, m, 64);
    if (lane == 0) amat[wvid + 4 * j][wvid + 4 * j] = d;
  }
  __syncthreads();

  { // out_intra[t][v] = sum_{s<=t} a[t][s] * vc[s][v]
    const int t0 = (tid >> 4) * 2, v0 = (tid & 15) * 4;
    float o00 = 0, o01 = 0, o02 = 0, o03 = 0, o10 = 0, o11 = 0, o12 = 0, o13 = 0;
    for (int s = 0; s < 32; s++) {
      float a0 = amat[t0][s], a1 = amat[t0 + 1][s];
      float b0 = vc[s][v0], b1 = vc[s][v0 + 1], b2 = vc[s][v0 + 2], b3 = vc[s][v0 + 3];
      o00 += a0 * b0; o01 += a0 * b1; o02 += a0 * b2; o03 += a0 * b3;
      o10 += a1 * b0; o11 += a1 * b1; o12 += a1 * b2; o13 += a1 * b3;
    }
    float* p0 = &outw[tbase + (long)t0 * 2048 + v0];
    float* p1 = &outw[tbase + (long)(t0 + 1) * 2048 + v0];
    p0[0] = o00; p0[1] = o01; p0[2] = o02; p0[3] = o03;
    p1[0] = o10; p1[1] = o11; p1[2] = o12; p1[3] = o13;
  }

  { // wkv[k][v] = sum_t (k*w_inter)[t][k] * vc[t][v]  -> overwrites r+k slots
    const int kk0 = (tid >> 4) * 4, v0 = (tid & 15) * 4;
    float a[4][4];
#pragma unroll
    for (int i = 0; i < 4; i++)
#pragma unroll
      for (int j = 0; j < 4; j++) a[i][j] = 0.f;
    for (int t = 0; t < 32; t++) {
      float w0 = wcum[t][kk0], w1 = wcum[t][kk0 + 1], w2 = wcum[t][kk0 + 2], w3 = wcum[t][kk0 + 3];
      float b0 = vc[t][v0], b1 = vc[t][v0 + 1], b2 = vc[t][v0 + 2], b3 = vc[t][v0 + 3];
      a[0][0] += w0 * b0; a[0][1] += w0 * b1; a[0][2] += w0 * b2; a[0][3] += w0 * b3;
      a[1][0] += w1 * b0; a[1][1] += w1 * b1; a[1][2] += w1 * b2; a[1][3] += w1 * b3;
      a[2][0] += w2 * b0; a[2][1] += w2 * b1; a[2][2] += w2 * b2; a[2][3] += w2 * b3;
      a[3][0] += w3 * b0; a[3][1] += w3 * b1; a[3][2] += w3 * b2; a[3][3] += w3 * b3;
    }
#pragma unroll
    for (int i = 0; i < 4; i++)
#pragma unroll
      for (int j = 0; j < 4; j++)
        recs[rec + (kk0 + i) * 64 + v0 + j] = f2bf(a[i][j]);
  }
}

// ---------------- sequential scan over chunks (in-place wkv->state) --------
// widened: 1024 blocks (8 k-groups of 8 rows), 2 accum/thread
__global__ __launch_bounds__(256) void k_scan(unsigned short* __restrict__ recs,
                                              const float* __restrict__ wsb,
                                              const float* __restrict__ kv0,
                                              float* __restrict__ finalst)
{
  const int bh = blockIdx.x >> 3;   // 128 (b,h)
  const int kq = blockIdx.x & 7;    // 8 groups of 8 k-rows
  const int tid = threadIdx.x;
  float st[2];
  const long base = (long)bh * 4096 + kq * 512;
#pragma unroll
  for (int j = 0; j < 2; j++) st[j] = kv0[base + j * 256 + tid];
  for (int n = 0; n < 64; n++) {
    const long cb = ((long)bh * 64 + n) * 6144 + kq * 512;
    const long wb = ((long)bh * 64 + n) * 64 + kq * 8;
#pragma unroll
    for (int j = 0; j < 2; j++) {
      int i = j * 256 + tid;
      unsigned short* p = &recs[cb + i];
      float wv = bf2f(*p);
      *p = f2bf(st[j]);                       // pre-update state
      st[j] = st[j] * wsb[wb + (i >> 6)] + wv;
    }
  }
#pragma unroll
  for (int j = 0; j < 2; j++) finalst[base + j * 256 + tid] = st[j];
}

// ---------------- inter-chunk contribution (MFMA, exact bf16 math) --------
// out[t][v] += sum_k rw[t][k] * st[k][v];  rw, st already bf16 in recs.
__global__ __launch_bounds__(256) void k_inter(const unsigned short* __restrict__ recs,
                                               float* __restrict__ outw)
{
  const int chunk = blockIdx.x;
  const int n = chunk & 63, bh = chunk >> 6;
  const int h = bh & 31, b = bh >> 5;
  const int tid = threadIdx.x;
  const int lane = tid & 63, w = tid >> 6;
  const int lm = lane & 15, quad = lane >> 4;
  const long rec = (long)chunk * 6144;
  const long tbase = ((long)(b * 2048 + n * 32)) * 2048 + h * 64;

  __shared__ __align__(16) unsigned short stT[64][72];  // B [v][k], 144B rows
  __shared__ __align__(16) unsigned short rwb[32][72];  // A [t][k]

  // rw: 2048 bf16, vector load + aligned LDS write
  {
    int4 rwv = *(const int4*)&recs[rec + 4096 + tid * 8];
    *(int4*)&rwb[tid >> 3][(tid & 7) * 8] = rwv;
  }
  // st: 4096 bf16, transpose into stT
  for (int ii = tid; ii < 4096; ii += 256)
    stT[ii & 63][ii >> 6] = recs[rec + ii];
  __syncthreads();

  // wave w: t-tile mi = w>>1, n-tiles {nset*2, nset*2+1}
  const int mi = w >> 1, nset = w & 1;
  bf16x8 aA[2], bB[2][2];
#pragma unroll
  for (int kk = 0; kk < 2; kk++) {
    aA[kk] = *(const bf16x8*)&rwb[mi * 16 + lm][kk * 32 + quad * 8];
#pragma unroll
    for (int p = 0; p < 2; p++)
      bB[p][kk] = *(const bf16x8*)&stT[(nset * 2 + p) * 16 + lm][kk * 32 + quad * 8];
  }
  f32x4 zero = {0.f, 0.f, 0.f, 0.f};
  f32x4 oc[2] = {zero, zero};
#pragma unroll
  for (int kk = 0; kk < 2; kk++) {
    oc[0] = __builtin_amdgcn_mfma_f32_16x16x32_bf16(aA[kk], bB[0][kk], oc[0], 0, 0, 0);
    oc[1] = __builtin_amdgcn_mfma_f32_16x16x32_bf16(aA[kk], bB[1][kk], oc[1], 0, 0, 0);
  }
#pragma unroll
  for (int p = 0; p < 2; p++) {
    int v = (nset * 2 + p) * 16 + lm;
#pragma unroll
    for (int r = 0; r < 4; r++) {
      int t = mi * 16 + quad * 4 + r;
      outw[tbase + (long)t * 2048 + v] += oc[p][r];
    }
  }
}

// ---------------- groupnorm(64) * g -> bf16 A for Wo GEMM ------------------
__global__ __launch_bounds__(256) void k_gnorm(const float* __restrict__ outw,
                                               const unsigned short* __restrict__ gb,
                                               const float* __restrict__ gnw,
                                               const float* __restrict__ gnb,
                                               unsigned short* __restrict__ aout)
{
  const int gid = blockIdx.x * 4 + (threadIdx.x >> 6); // over B*T*H
  const int lane = threadIdx.x & 63;
  const long bt = gid >> 5;
  const int h = gid & 31;
  const int c = h * 64 + lane;
  const long off = bt * 2048 + c;
  float y = outw[off];
  float s = y, sq = y * y;
#pragma unroll
  for (int m = 32; m; m >>= 1) {
    s += __shfl_xor(s, m, 64);
    sq += __shfl_xor(sq, m, 64);
  }
  float mu = s * (1.f / 64.f);
  float var = sq * (1.f / 64.f) - mu * mu;
  float nrm = (y - mu) * rsqrtf(var + 6.4e-4f);
  float o = (nrm * gnw[c] + gnb[c]) * bf2f(gb[off]);
  aout[off] = f2bf(o);
}

// ---------------- host ------------------------------------------------------
extern "C" void kernel_launch(void* const* d_in, const int* in_sizes, int n_in,
                              void* d_out, int out_size, void* d_ws, size_t ws_size,
                              hipStream_t stream)
{
  const float* x     = (const float*)d_in[0];
  const float* shift = (const float*)d_in[1];
  const float* kv0   = (const float*)d_in[2];
  const float* maax  = (const float*)d_in[3];
  const float* maaw  = (const float*)d_in[4];
  const float* maak  = (const float*)d_in[5];
  const float* maav  = (const float*)d_in[6];
  const float* maar  = (const float*)d_in[7];
  const float* maag  = (const float*)d_in[8];
  const float* w1    = (const float*)d_in[9];
  const float* w2    = (const float*)d_in[10];
  const float* tdec  = (const float*)d_in[11];
  const float* tdw1  = (const float*)d_in[12];
  const float* tdw2  = (const float*)d_in[13];
  const float* u     = (const float*)d_in[14];
  const float* Wr    = (const float*)d_in[15];
  const float* Wk    = (const float*)d_in[16];
  const float* Wv    = (const float*)d_in[17];
  const float* Wg    = (const float*)d_in[18];
  const float* Wo    = (const float*)d_in[19];
  const float* gnw   = (const float*)d_in[20];
  const float* gnb   = (const float*)d_in[21];

  char* ws = (char*)d_ws;
  const size_t MB = 1048576;
  unsigned short* WbfR  = (unsigned short*)(ws + 0 * MB);
  unsigned short* WbfK  = (unsigned short*)(ws + 8 * MB);
  unsigned short* WbfV  = (unsigned short*)(ws + 16 * MB);
  unsigned short* WbfG  = (unsigned short*)(ws + 24 * MB);
  unsigned short* WbfO  = (unsigned short*)(ws + 32 * MB);
  unsigned short* w2tb  = (unsigned short*)(ws + 40 * MB);
  unsigned short* w1t   = (unsigned short*)(ws + 40 * MB + 655360);
  unsigned short* tdw1t = (unsigned short*)(ws + 40 * MB + 1310720);
  unsigned short* tdw2t = (unsigned short*)(ws + 40 * MB + 1572864);
  unsigned short* xxxb  = (unsigned short*)(ws + 40 * MB + 1835008);
  unsigned short* t1b   = (unsigned short*)(ws + 40 * MB + 4456448);
  float*          wsb   = (float*)(ws + 40 * MB + 5505024);
  unsigned short* xmixb = (unsigned short*)(ws + 48 * MB);
  _Float16*       wlb   = (_Float16*)(ws + 48 * MB);
  unsigned short* x1b   = (unsigned short*)(ws + 80 * MB);
  unsigned short* aob   = (unsigned short*)(ws + 80 * MB);
  unsigned short* recs  = (unsigned short*)(ws + 112 * MB);
  unsigned short* gbuf  = recs;

  float* outp    = (float*)d_out;
  float* xlast   = outp + 16777216;
  float* finalst = outp + 16777216 + 8192;

  // weights -> bf16
  k_convert<<<4096, 256, 0, stream>>>(Wr, WbfR, 1048576);
  k_convert<<<4096, 256, 0, stream>>>(Wk, WbfK, 1048576);
  k_convert<<<4096, 256, 0, stream>>>(Wv, WbfV, 1048576);
  k_convert<<<4096, 256, 0, stream>>>(Wg, WbfG, 1048576);
  k_convert<<<4096, 256, 0, stream>>>(Wo, WbfO, 1048576);
  // transposes
  k_transpose<<<1280, 256, 0, stream>>>(w1, w1t, 2048, 160);
  k_transpose<<<512, 256, 0, stream>>>(tdw1, tdw1t, 2048, 64);
  k_transpose<<<512, 256, 0, stream>>>(tdw2, tdw2t, 64, 2048);
  for (int f = 0; f < 5; f++)
    k_transpose<<<256, 256, 0, stream>>>(w2 + (long)f * 65536, w2tb + (long)f * 65536, 32, 2048);

  // prep + x_last
  k_prep<<<16384, 256, 0, stream>>>(x, shift, maax, xmixb, xlast);
  // xxx = tanh(xmix @ w1^T)
  gemm_nt<2, true><<<dim3(2, 64), 256, 0, stream>>>(xmixb, w1t, xxxb, 8192, 160, 2048, nullptr, 0);

  // f=0 (w): mix -> decay chain -> wlog (f16, over dead xmixb)
  k_mix1<<<dim3(16, 64), 256, 0, stream>>>(xxxb, w2tb, x, shift, maaw, x1b, 0);
  gemm_nt<2, true><<<dim3(1, 64), 256, 0, stream>>>(x1b, tdw1t, t1b, 8192, 64, 2048, nullptr, 0);
  gemm_nt<4, false><<<dim3(16, 64), 256, 0, stream>>>(t1b, tdw2t, wlb, 8192, 2048, 64, tdec, 0);
  // f=1 (k)
  k_mix1<<<dim3(16, 64), 256, 0, stream>>>(xxxb, w2tb, x, shift, maak, x1b, 1);
  gemm256_nt<5><<<dim3(8, 32), 512, 0, stream>>>(x1b, WbfK, recs, 8192, 2048, 2048, 2048);
  // f=2 (v)
  k_mix1<<<dim3(16, 64), 256, 0, stream>>>(xxxb, w2tb, x, shift, maav, x1b, 2);
  gemm256_nt<5><<<dim3(8, 32), 512, 0, stream>>>(x1b, WbfV, recs, 8192, 2048, 2048, 4096);
  // f=3 (r)
  k_mix1<<<dim3(16, 64), 256, 0, stream>>>(xxxb, w2tb, x, shift, maar, x1b, 3);
  gemm256_nt<5><<<dim3(8, 32), 512, 0, stream>>>(x1b, WbfR, recs, 8192, 2048, 2048, 0);
  // f=4 (g): x1b holds xg until the G GEMM below
  k_mix1<<<dim3(16, 64), 256, 0, stream>>>(xxxb, w2tb, x, shift, maag, x1b, 4);

  // chunked rwkv (outw accumulated f32 directly in d_out)
  k_chunk<<<8192, 256, 0, stream>>>(recs, wlb, u, outp, wsb);
  k_scan<<<1024, 256, 0, stream>>>(recs, wsb, kv0, finalst);
  k_inter<<<8192, 256, 0, stream>>>(recs, outp);

  // g = silu(xg @ Wg^T) (records dead -> gbuf), then groupnorm*g, then Wo
  gemm256_nt<3><<<dim3(8, 32), 512, 0, stream>>>(x1b, WbfG, gbuf, 8192, 2048, 2048, 0);
  k_gnorm<<<65536, 256, 0, stream>>>(outp, gbuf, gnw, gnb, aob);
  gemm256_nt<0><<<dim3(8, 32), 512, 0, stream>>>(aob, WbfO, outp, 8192, 2048, 2048, 0);
}